// Round 4
// baseline (519.394 us; speedup 1.0000x reference)
//
#include <hip/hip_runtime.h>
#include <hip/hip_bf16.h>
#include <cstdint>
#include <cstddef>

// ---------------------------------------------------------------------------
// BDH Linear Attention (B=8,N=1024,D=768,H=8,S=3072,HD=384) on gfx950
// Round 4: shared GEMM mainloop upgraded to double-buffered 2-phase prefetch
//          (one barrier per K-step) + pair-row XOR LDS swizzle (bank-conflict
//          fix, swizzle on global-source + read side; LDS dest stays linear).
// ---------------------------------------------------------------------------

typedef __bf16 bf16_t;
typedef bf16_t bf16x4 __attribute__((ext_vector_type(4)));
typedef bf16_t bf16x8 __attribute__((ext_vector_type(8)));
typedef float f32x4 __attribute__((ext_vector_type(4)));

// ---------------- shared GEMM mainloop: C[128x128] += A @ BT^T --------------
// A: [M,K] row-major bf16 (lda), BT: [N,K] row-major bf16 (ldb), K % 32 == 0.
// 256 threads = 4 waves (2x2), each wave 64x64 = 4x4 frags of 16x16x32.
// LDS per tile-buffer: 128 rows x 32 cols bf16 = 8KB, physical layout:
//   chunk q (16 rows) at [1024*q, 1024*q+1024) bytes; within chunk, row pair
//   pr (rows 2pr,2pr+1) at [128*pr,128*pr+128); 16B slot p holds logical
//   (e,c) with p = (e*4+c) ^ pr.  Staged via linear global_load_lds with the
//   inverse permutation applied to the GLOBAL source address.
__device__ __forceinline__ void gemm128_bt(
    const bf16_t* __restrict__ A, int lda,
    const bf16_t* __restrict__ BT, int ldb,
    int K, int row0, int col0,
    bf16_t* As, bf16_t* Bs, f32x4 acc[4][4])
{
    const int t    = threadIdx.x;
    const int lane = t & 63;
    const int wid  = t >> 6;
    const int wr   = wid >> 1, wc = wid & 1;

    // staging constants: lane -> (pair row offset, src col chunk)
    const int spr  = lane >> 3;                 // pair index 0..7 in 16-row chunk
    const int sl   = (lane & 7) ^ spr;          // logical slot
    const int srow = spr * 2 + (sl >> 2);       // row offset 0..15 within chunk
    const int scol = (sl & 3) * 8;              // elem col offset 0/8/16/24
    const int q0 = wid * 2, q1 = wid * 2 + 1;   // this wave's 16-row chunks

    // read constants: logical (row=..+fr, kgroup g) -> swizzled elem offset
    const int fr = lane & 15;
    const int g  = lane >> 4;
    const int rswz = (fr >> 1) * 64 + (((((fr & 1) << 2) + g)) ^ (fr >> 1)) * 8;

#pragma unroll
    for (int m = 0; m < 4; ++m)
#pragma unroll
        for (int n = 0; n < 4; ++n)
            acc[m][n] = (f32x4){0.f, 0.f, 0.f, 0.f};

    auto stage = [&](int buf, int k0) {
        bf16_t* dA = As + buf * 4096;
        bf16_t* dB = Bs + buf * 4096;
        __builtin_amdgcn_global_load_lds(
            (const __attribute__((address_space(1))) void*)(A + (size_t)(row0 + q0 * 16 + srow) * lda + (k0 + scol)),
            (__attribute__((address_space(3))) void*)(dA + q0 * 512), 16, 0, 0);
        __builtin_amdgcn_global_load_lds(
            (const __attribute__((address_space(1))) void*)(A + (size_t)(row0 + q1 * 16 + srow) * lda + (k0 + scol)),
            (__attribute__((address_space(3))) void*)(dA + q1 * 512), 16, 0, 0);
        __builtin_amdgcn_global_load_lds(
            (const __attribute__((address_space(1))) void*)(BT + (size_t)(col0 + q0 * 16 + srow) * ldb + (k0 + scol)),
            (__attribute__((address_space(3))) void*)(dB + q0 * 512), 16, 0, 0);
        __builtin_amdgcn_global_load_lds(
            (const __attribute__((address_space(1))) void*)(BT + (size_t)(col0 + q1 * 16 + srow) * ldb + (k0 + scol)),
            (__attribute__((address_space(3))) void*)(dB + q1 * 512), 16, 0, 0);
    };

    stage(0, 0);
    __syncthreads();                 // vmcnt(0)+barrier: buf0 ready

    int cur = 0;
    for (int k0 = 0; k0 < K; k0 += 32) {
        if (k0 + 32 < K) stage(cur ^ 1, k0 + 32);   // prefetch next tile

        const bf16_t* sa = As + cur * 4096;
        const bf16_t* sb = Bs + cur * 4096;
        bf16x8 av[4], bv[4];
#pragma unroll
        for (int m = 0; m < 4; ++m)
            av[m] = *(const bf16x8*)&sa[(wr * 4 + m) * 512 + rswz];
#pragma unroll
        for (int n = 0; n < 4; ++n)
            bv[n] = *(const bf16x8*)&sb[(wc * 4 + n) * 512 + rswz];
#pragma unroll
        for (int m = 0; m < 4; ++m)
#pragma unroll
            for (int n = 0; n < 4; ++n)
                acc[m][n] = __builtin_amdgcn_mfma_f32_16x16x32_bf16(av[m], bv[n], acc[m][n], 0, 0, 0);

        __syncthreads();             // drains prefetch vmcnt + protects LDS
        cur ^= 1;
    }
}

__device__ __forceinline__ int xcd_swz(int bid, int nwg) {
    // nwg % 8 == 0 (bijective)
    const int cpx = nwg >> 3;
    return (bid & 7) * cpx + (bid >> 3);
}

// ---------------- small kernels --------------------------------------------

// transpose-cast: in f32 [R,C] -> out bf16 [C,R]
__global__ void ktrans_w(const float* __restrict__ in, bf16_t* __restrict__ out, int R, int C)
{
    __shared__ float tl[32][33];
    const int c0 = blockIdx.x * 32, r0 = blockIdx.y * 32;
    const int tx = threadIdx.x, ty = threadIdx.y;
#pragma unroll
    for (int i = ty; i < 32; i += 8) tl[i][tx] = in[(size_t)(r0 + i) * C + c0 + tx];
    __syncthreads();
#pragma unroll
    for (int i = ty; i < 32; i += 8) out[(size_t)(c0 + i) * R + r0 + tx] = (bf16_t)tl[tx][i];
}

__device__ __forceinline__ float block_sum256(float v, float* s4)
{
#pragma unroll
    for (int off = 32; off > 0; off >>= 1) v += __shfl_down(v, off);
    const int lane = threadIdx.x & 63, w = threadIdx.x >> 6;
    if (lane == 0) s4[w] = v;
    __syncthreads();
    return s4[0] + s4[1] + s4[2] + s4[3];
}

// LayerNorm (biased var) + residue gate, one block per row (b,n)
__global__ void __launch_bounds__(256) kln(
    const float* __restrict__ x, const float* __restrict__ g, const float* __restrict__ bt,
    const float* __restrict__ w_res, const float* __restrict__ b_res,
    bf16_t* __restrict__ xn, float* __restrict__ residue)
{
    __shared__ float red[12];
    const int row = blockIdx.x;
    const float* xr = x + (size_t)row * 768;
    const int t = threadIdx.x;
    const float v0 = xr[t], v1 = xr[t + 256], v2 = xr[t + 512];
    const float ts  = block_sum256(v0 + v1 + v2, red);
    const float ts2 = block_sum256(v0 * v0 + v1 * v1 + v2 * v2, red + 4);
    const float mu  = ts * (1.f / 768.f);
    const float var = ts2 * (1.f / 768.f) - mu * mu;
    const float rs  = rsqrtf(var + 1e-5f);
    float dot = 0.f;
    {
        float xv;
        xv = (v0 - mu) * rs * g[t]       + bt[t];       xn[(size_t)row * 768 + t]       = (bf16_t)xv; dot += xv * w_res[t];
        xv = (v1 - mu) * rs * g[t + 256] + bt[t + 256]; xn[(size_t)row * 768 + t + 256] = (bf16_t)xv; dot += xv * w_res[t + 256];
        xv = (v2 - mu) * rs * g[t + 512] + bt[t + 512]; xn[(size_t)row * 768 + t + 512] = (bf16_t)xv; dot += xv * w_res[t + 512];
    }
    const float td = block_sum256(dot, red + 8);
    if (t == 0) residue[row] = 1.f / (1.f + expf(-(td + b_res[0])));
}

// column mean accumulate: xmean[b,d] += sum over 128 tokens
__global__ void kcolmean(const bf16_t* __restrict__ xn, float* __restrict__ xmean)
{
    const int b = blockIdx.x, dc = blockIdx.y, nc = blockIdx.z;
    const int d = dc * 256 + threadIdx.x;
    const bf16_t* p = xn + (size_t)(b * 1024 + nc * 128) * 768 + d;
    float s = 0.f;
#pragma unroll 4
    for (int n = 0; n < 128; ++n) s += (float)p[(size_t)n * 768];
    atomicAdd(&xmean[b * 768 + d], s);
}

// read/write gates + wmean; one block of 64 threads (b,h)
__global__ void kgates(const float* __restrict__ xmean,
                       const float* __restrict__ w_rg, const float* __restrict__ b_rg,
                       const float* __restrict__ w_wg, const float* __restrict__ b_wg,
                       float* __restrict__ read_g, float* __restrict__ wmean)
{
    __shared__ float wg[64];
    const int t = threadIdx.x, b = t >> 3, h = t & 7;
    float dr = 0.f, dw = 0.f;
    for (int d = 0; d < 768; ++d) {
        const float xm = xmean[b * 768 + d] * (1.f / 1024.f);
        dr += xm * w_rg[d * 8 + h];
        dw += xm * w_wg[d * 8 + h];
    }
    read_g[t] = 1.f / (1.f + expf(-(dr + b_rg[h])));
    wg[t]     = 1.f / (1.f + expf(-(dw + b_wg[h])));
    __syncthreads();
    if (t < 8) {
        float s = 0.f;
#pragma unroll
        for (int b2 = 0; b2 < 8; ++b2) s += wg[b2 * 8 + t];
        wmean[t] = s * 0.125f;
    }
}

// qkv GEMM over a CHUNK of batches.
__global__ void __launch_bounds__(256) kgemm_qkv(
    const bf16_t* __restrict__ xnc, const bf16_t* __restrict__ w_inT,
    const float* __restrict__ b_in,
    bf16_t* __restrict__ qfc, bf16_t* __restrict__ kTc, bf16_t* __restrict__ vTc,
    float* __restrict__ ksum_c, int nrt /* CHUNK*8 row tiles */)
{
    __shared__ __align__(16) bf16_t As[8192], Bs[8192];
    int flat = blockIdx.y * 72 + blockIdx.x;
    flat = xcd_swz(flat, 72 * nrt);
    const int bx = flat % 72, by = flat / 72;
    const int row0 = by * 128, col0 = bx * 128;
    f32x4 acc[4][4];
    gemm128_bt(xnc, 768, w_inT, 768, 768, row0, col0, As, Bs, acc);

    const int lane = threadIdx.x & 63, wid = threadIdx.x >> 6;
    const int wr = wid >> 1, wc = wid & 1;
    const int third = col0 / 3072;

    if (third == 0) {
        // q path: bias + phi, row-major store
#pragma unroll
        for (int m = 0; m < 4; ++m) {
#pragma unroll
            for (int n2 = 0; n2 < 4; ++n2) {
                const int col  = col0 + wc * 64 + n2 * 16 + (lane & 15);
                const float bias = b_in[col];
#pragma unroll
                for (int r = 0; r < 4; ++r) {
                    const int row = row0 + wr * 64 + m * 16 + (lane >> 4) * 4 + r;
                    const float v = acc[m][n2][r] + bias;
                    const float u = fmaxf(v, 0.f) + 1e-6f;
                    qfc[(size_t)row * 3072 + col] = (bf16_t)(u * sqrtf(u));
                }
            }
        }
    } else {
        // k/v path: bias (+phi for k), transposed store [bh][d][n], ksum atomics
        const int lb  = row0 >> 10;                 // local batch
        const int nb  = (row0 & 1023) + wr * 64 + (lane >> 4) * 4;
        const int sl0 = col0 - third * 3072;        // 0..3071
        const int h   = sl0 / 384;
        bf16_t* dstT = ((third == 1) ? kTc : vTc) + (size_t)(lb * 8 + h) * 384 * 1024;
        float* ksrow = ksum_c + (size_t)(lb * 8 + h) * 384;
#pragma unroll
        for (int n2 = 0; n2 < 4; ++n2) {
            const int d   = (sl0 % 384) + wc * 64 + n2 * 16 + (lane & 15);
            const int col = col0 + wc * 64 + n2 * 16 + (lane & 15);
            const float bias = b_in[col];
            float ksp = 0.f;
#pragma unroll
            for (int m = 0; m < 4; ++m) {
                bf16x4 pk;
#pragma unroll
                for (int r = 0; r < 4; ++r) {
                    float v = acc[m][n2][r] + bias;
                    if (third == 1) { const float u = fmaxf(v, 0.f) + 1e-6f; v = u * sqrtf(u); ksp += v; }
                    pk[r] = (bf16_t)v;
                }
                *(bf16x4*)&dstT[(size_t)d * 1024 + nb + m * 16] = pk;
            }
            if (third == 1) atomicAdd(&ksrow[d], ksp);
        }
    }
}

// state GEMM per local (b,h): C[d,e] = sum_n kT[d,n] vT[e,n];
// scale rows by 1/(ksum+eps), accumulate into ssum[h]
__global__ void __launch_bounds__(256) kgemm_state(
    const bf16_t* __restrict__ kTc, const bf16_t* __restrict__ vTc,
    const float* __restrict__ ksum_c, float* __restrict__ ssum)
{
    __shared__ __align__(16) bf16_t As[8192], Bs[8192];
    const int lbh = blockIdx.z, h = lbh & 7;
    const int row0 = blockIdx.y * 128, col0 = blockIdx.x * 128;
    const bf16_t* A  = kTc + (size_t)lbh * 393216;
    const bf16_t* BT = vTc + (size_t)lbh * 393216;
    f32x4 acc[4][4];
    gemm128_bt(A, 1024, BT, 1024, 1024, row0, col0, As, Bs, acc);

    const int lane = threadIdx.x & 63, wid = threadIdx.x >> 6;
    const int wr = wid >> 1, wc = wid & 1;
    float* ss = ssum + (size_t)h * 147456;
#pragma unroll
    for (int m = 0; m < 4; ++m) {
#pragma unroll
        for (int r = 0; r < 4; ++r) {
            const int d = row0 + wr * 64 + m * 16 + (lane >> 4) * 4 + r;
            const float sc = 1.f / (ksum_c[(size_t)lbh * 384 + d] + 1e-6f);
#pragma unroll
            for (int n = 0; n < 4; ++n) {
                const int e = col0 + wc * 64 + n * 16 + (lane & 15);
                atomicAdd(&ss[(size_t)d * 384 + e], acc[m][n][r] * sc);
            }
        }
    }
}

// mem_newT[h,e,d] = bf16(0.95*mem[h,d,e] + (0.05*wmean[h]/8)*ssum[h,d,e])
__global__ void kmemupd(const float* __restrict__ mem, const float* __restrict__ ssum,
                        const float* __restrict__ wmean, bf16_t* __restrict__ memT)
{
    __shared__ float tl[32][33];
    const int h = blockIdx.z;
    const int e0 = blockIdx.x * 32, d0 = blockIdx.y * 32;
    const int tx = threadIdx.x, ty = threadIdx.y;
    const size_t base = (size_t)h * 147456;
    const float wm = wmean[h] * (0.05f / 8.f);
#pragma unroll
    for (int i = ty; i < 32; i += 8) {
        const size_t idx = base + (size_t)(d0 + i) * 384 + e0 + tx;
        tl[i][tx] = 0.95f * mem[idx] + wm * ssum[idx];
    }
    __syncthreads();
#pragma unroll
    for (int i = ty; i < 32; i += 8)
        memT[base + (size_t)(e0 + i) * 384 + d0 + tx] = (bf16_t)tl[tx][i];
}

// y GEMM: per (b,h) C[n,e] = q[n,:] @ memT[e,:]; scale by read gate
__global__ void __launch_bounds__(256) kgemm_y(
    const bf16_t* __restrict__ qf, const bf16_t* __restrict__ memT,
    const float* __restrict__ read_g, bf16_t* __restrict__ yf)
{
    __shared__ __align__(16) bf16_t As[8192], Bs[8192];
    const int bh = blockIdx.z, b = bh >> 3, h = bh & 7;
    const int row0 = blockIdx.y * 128, col0 = blockIdx.x * 128;
    const bf16_t* A  = qf + (size_t)b * 1024 * 3072 + (size_t)h * 384;
    const bf16_t* BT = memT + (size_t)h * 147456;
    f32x4 acc[4][4];
    gemm128_bt(A, 3072, BT, 384, 384, row0, col0, As, Bs, acc);

    const float rg = read_g[bh];
    const int lane = threadIdx.x & 63, wid = threadIdx.x >> 6;
    const int wr = wid >> 1, wc = wid & 1;
#pragma unroll
    for (int m = 0; m < 4; ++m) {
#pragma unroll
        for (int n = 0; n < 4; ++n) {
            const int col = col0 + wc * 64 + n * 16 + (lane & 15);
#pragma unroll
            for (int r = 0; r < 4; ++r) {
                const int row = row0 + wr * 64 + m * 16 + (lane >> 4) * 4 + r;
                yf[(size_t)(b * 1024 + row) * 3072 + h * 384 + col] = (bf16_t)(acc[m][n][r] * rg);
            }
        }
    }
}

// out GEMM: C = yf @ w_out + b_out; out = residue*C + (1-residue)*x
__global__ void __launch_bounds__(256) kgemm_out(
    const bf16_t* __restrict__ yf, const bf16_t* __restrict__ w_outT,
    const float* __restrict__ b_out, const float* __restrict__ residue,
    const float* __restrict__ x, float* __restrict__ out)
{
    __shared__ __align__(16) bf16_t As[8192], Bs[8192];
    int flat = blockIdx.y * 6 + blockIdx.x;
    flat = xcd_swz(flat, 384);
    const int bx = flat % 6, by = flat / 6;
    const int row0 = by * 128, col0 = bx * 128;
    f32x4 acc[4][4];
    gemm128_bt(yf, 3072, w_outT, 3072, 3072, row0, col0, As, Bs, acc);

    const int lane = threadIdx.x & 63, wid = threadIdx.x >> 6;
    const int wr = wid >> 1, wc = wid & 1;
#pragma unroll
    for (int m = 0; m < 4; ++m) {
#pragma unroll
        for (int n = 0; n < 4; ++n) {
            const int col = col0 + wc * 64 + n * 16 + (lane & 15);
            const float bias = b_out[col];
#pragma unroll
            for (int r = 0; r < 4; ++r) {
                const int row = row0 + wr * 64 + m * 16 + (lane >> 4) * 4 + r;
                const float v = acc[m][n][r] + bias;
                const float rr = residue[row];
                out[(size_t)row * 768 + col] = rr * v + (1.f - rr) * x[(size_t)row * 768 + col];
            }
        }
    }
}

// ---------------------------------------------------------------------------
extern "C" void kernel_launch(void* const* d_in, const int* in_sizes, int n_in,
                              void* d_out, int out_size, void* d_ws, size_t ws_size,
                              hipStream_t stream)
{
    (void)in_sizes; (void)n_in; (void)out_size;
    const float* x     = (const float*)d_in[0];
    const float* mem   = (const float*)d_in[1];
    const float* ln_g  = (const float*)d_in[2];
    const float* ln_b  = (const float*)d_in[3];
    const float* w_in  = (const float*)d_in[4];
    const float* b_in  = (const float*)d_in[5];
    const float* w_out = (const float*)d_in[6];
    const float* b_out = (const float*)d_in[7];
    const float* w_rg  = (const float*)d_in[8];
    const float* b_rg  = (const float*)d_in[9];
    const float* w_wg  = (const float*)d_in[10];
    const float* b_wg  = (const float*)d_in[11];
    const float* w_res = (const float*)d_in[12];
    const float* b_res = (const float*)d_in[13];
    float* out = (float*)d_out;

    // pick largest CHUNK (batches per qkv/state launch pair) that fits ws
    auto total_for = [&](int c) -> size_t {
        size_t o = 0;
        auto a = [&](size_t b) { o += (b + 255) & ~(size_t)255; };
        a(50331648);                       // qf
        a(14155776); a(12582912);          // w_inT, xn (overlay head)
        a((size_t)c * 6291456);            // kTc
        a((size_t)c * 6291456);            // vTc
        a(4718592); a(4718592); a(2359296);// w_outT, ssum, memT
        a(32768); a(24576); a(98304); a(256); a(256); // residue,xmean,ksum,read_g,wmean
        return o;
    };
    int CHUNK = 0;
    for (int c = 8; c >= 2; c >>= 1) if (total_for(c) <= ws_size) { CHUNK = c; break; }
    if (CHUNK == 0) return;                // fail soft

    char* ws = (char*)d_ws;
    size_t off = 0;
    auto alloc = [&](size_t bytes) -> char* {
        char* p = ws + off; off += (bytes + 255) & ~(size_t)255; return p;
    };
    bf16_t* qf     = (bf16_t*)alloc(50331648);
    bf16_t* yf     = (bf16_t*)(ws + off);   // overlay: w_inT..vTc (>= 48 MB for CHUNK>=2)
    bf16_t* w_inT  = (bf16_t*)alloc(14155776);
    bf16_t* xn     = (bf16_t*)alloc(12582912);
    bf16_t* kTc    = (bf16_t*)alloc((size_t)CHUNK * 6291456);
    bf16_t* vTc    = (bf16_t*)alloc((size_t)CHUNK * 6291456);
    bf16_t* w_outT = (bf16_t*)alloc(4718592);
    float*  ssum   = (float*) alloc(4718592);
    bf16_t* memT   = (bf16_t*)alloc(2359296);
    float*  residue= (float*) alloc(32768);
    float*  xmean  = (float*) alloc(24576);
    float*  ksum   = (float*) alloc(98304);          // [64][384] global bh
    float*  read_g = (float*) alloc(256);
    float*  wmean  = (float*) alloc(256);

    hipMemsetAsync(xmean, 0, 24576, stream);
    hipMemsetAsync(ksum,  0, 98304, stream);
    hipMemsetAsync(ssum,  0, 4718592, stream);

    ktrans_w<<<dim3(288, 24), dim3(32, 8), 0, stream>>>(w_in, w_inT, 768, 9216);
    ktrans_w<<<dim3(24, 96), dim3(32, 8), 0, stream>>>(w_out, w_outT, 3072, 768);
    kln<<<8192, 256, 0, stream>>>(x, ln_g, ln_b, w_res, b_res, xn, residue);
    kcolmean<<<dim3(8, 3, 8), 256, 0, stream>>>(xn, xmean);
    kgates<<<1, 64, 0, stream>>>(xmean, w_rg, b_rg, w_wg, b_wg, read_g, wmean);

    const int NC = 8 / CHUNK;
    for (int c = 0; c < NC; ++c) {
        const int b0 = c * CHUNK;
        kgemm_qkv<<<dim3(72, CHUNK * 8), 256, 0, stream>>>(
            xn + (size_t)b0 * 1024 * 768, w_inT, b_in,
            qf + (size_t)b0 * 1024 * 3072, kTc, vTc,
            ksum + (size_t)b0 * 8 * 384, CHUNK * 8);
        kgemm_state<<<dim3(3, 3, CHUNK * 8), 256, 0, stream>>>(
            kTc, vTc, ksum + (size_t)b0 * 8 * 384, ssum);
    }

    kmemupd<<<dim3(12, 12, 8), dim3(32, 8), 0, stream>>>(mem, ssum, wmean, memT);
    kgemm_y<<<dim3(3, 8, 64), 256, 0, stream>>>(qf, memT, read_g, yf);
    kgemm_out<<<dim3(6, 64), 256, 0, stream>>>(yf, w_outT, b_out, residue, x, out);
}

// Round 5
// 480.438 us; speedup vs baseline: 1.0811x; 1.0811x over previous
//
#include <hip/hip_runtime.h>
#include <hip/hip_bf16.h>
#include <cstdint>
#include <cstddef>

// ---------------------------------------------------------------------------
// BDH Linear Attention (B=8,N=1024,D=768,H=8,S=3072,HD=384) on gfx950
// Round 5: revert mainloop to r3's proven single-buffer form (r4's dbuf+swz
//          regressed: T2/T3 null at 2-phase, m233/m252); add XCD band remap
//          so each XCD keeps its A-row-panels L2-resident and streams B once.
// ---------------------------------------------------------------------------

typedef __bf16 bf16_t;
typedef bf16_t bf16x4 __attribute__((ext_vector_type(4)));
typedef bf16_t bf16x8 __attribute__((ext_vector_type(8)));
typedef float f32x4 __attribute__((ext_vector_type(4)));

// ---------------- shared GEMM mainloop: C[128x128] += A @ BT^T --------------
// A: [M,K] row-major bf16 (lda), BT: [N,K] row-major bf16 (ldb), K % 32 == 0.
// 256 threads = 4 waves (2x2), each wave 64x64 = 4x4 frags of 16x16x32.
__device__ __forceinline__ void gemm128_bt(
    const bf16_t* __restrict__ A, int lda,
    const bf16_t* __restrict__ BT, int ldb,
    int K, int row0, int col0,
    bf16_t* As, bf16_t* Bs, f32x4 acc[4][4])
{
    const int t    = threadIdx.x;
    const int lane = t & 63;
    const int wid  = t >> 6;
    const int wr   = wid >> 1, wc = wid & 1;
    const int fr   = lane & 15;            // fragment row
    const int fk   = (lane >> 4) * 8;      // fragment k offset

#pragma unroll
    for (int m = 0; m < 4; ++m)
#pragma unroll
        for (int n = 0; n < 4; ++n)
            acc[m][n] = (f32x4){0.f, 0.f, 0.f, 0.f};

    const int rr = lane >> 2;              // 0..15 row within 16-row chunk
    const int rc = (lane & 3) * 8;         // 0,8,16,24 element col

    for (int k0 = 0; k0 < K; k0 += 32) {
#pragma unroll
        for (int c = 0; c < 2; ++c) {
            const int q = wid * 2 + c;     // 16-row chunk id, wave-uniform
            __builtin_amdgcn_global_load_lds(
                (const __attribute__((address_space(1))) void*)(A + (size_t)(row0 + q * 16 + rr) * lda + (k0 + rc)),
                (__attribute__((address_space(3))) void*)(As + q * 512), 16, 0, 0);
            __builtin_amdgcn_global_load_lds(
                (const __attribute__((address_space(1))) void*)(BT + (size_t)(col0 + q * 16 + rr) * ldb + (k0 + rc)),
                (__attribute__((address_space(3))) void*)(Bs + q * 512), 16, 0, 0);
        }
        __syncthreads();   // drains vmcnt -> staged data visible

        bf16x8 av[4], bv[4];
#pragma unroll
        for (int m = 0; m < 4; ++m)
            av[m] = *(const bf16x8*)&As[(wr * 64 + m * 16 + fr) * 32 + fk];
#pragma unroll
        for (int n = 0; n < 4; ++n)
            bv[n] = *(const bf16x8*)&Bs[(wc * 64 + n * 16 + fr) * 32 + fk];
#pragma unroll
        for (int m = 0; m < 4; ++m)
#pragma unroll
            for (int n = 0; n < 4; ++n)
                acc[m][n] = __builtin_amdgcn_mfma_f32_16x16x32_bf16(av[m], bv[n], acc[m][n], 0, 0, 0);
        __syncthreads();   // protect LDS before next stage
    }
}

// XCD band remap: flat dispatch id -> (bx, by) such that XCD x (= flat&7,
// round-robin dispatch) owns by-band [x*nby/8, (x+1)*nby/8) for ALL bx,
// issued bx-major: A-panels of the band stay L2-resident, B streams once.
// Requires nby % 8 == 0.
__device__ __forceinline__ void band_map(int flat, int nby, int& bx, int& by)
{
    const int xcd = flat & 7;
    const int seq = flat >> 3;
    const int bandsz = nby >> 3;
    by = xcd * bandsz + (seq % bandsz);
    bx = seq / bandsz;
}

// ---------------- small kernels --------------------------------------------

// transpose-cast: in f32 [R,C] -> out bf16 [C,R]
__global__ void ktrans_w(const float* __restrict__ in, bf16_t* __restrict__ out, int R, int C)
{
    __shared__ float tl[32][33];
    const int c0 = blockIdx.x * 32, r0 = blockIdx.y * 32;
    const int tx = threadIdx.x, ty = threadIdx.y;
#pragma unroll
    for (int i = ty; i < 32; i += 8) tl[i][tx] = in[(size_t)(r0 + i) * C + c0 + tx];
    __syncthreads();
#pragma unroll
    for (int i = ty; i < 32; i += 8) out[(size_t)(c0 + i) * R + r0 + tx] = (bf16_t)tl[tx][i];
}

__device__ __forceinline__ float block_sum256(float v, float* s4)
{
#pragma unroll
    for (int off = 32; off > 0; off >>= 1) v += __shfl_down(v, off);
    const int lane = threadIdx.x & 63, w = threadIdx.x >> 6;
    if (lane == 0) s4[w] = v;
    __syncthreads();
    return s4[0] + s4[1] + s4[2] + s4[3];
}

// LayerNorm (biased var) + residue gate, one block per row (b,n)
__global__ void __launch_bounds__(256) kln(
    const float* __restrict__ x, const float* __restrict__ g, const float* __restrict__ bt,
    const float* __restrict__ w_res, const float* __restrict__ b_res,
    bf16_t* __restrict__ xn, float* __restrict__ residue)
{
    __shared__ float red[12];
    const int row = blockIdx.x;
    const float* xr = x + (size_t)row * 768;
    const int t = threadIdx.x;
    const float v0 = xr[t], v1 = xr[t + 256], v2 = xr[t + 512];
    const float ts  = block_sum256(v0 + v1 + v2, red);
    const float ts2 = block_sum256(v0 * v0 + v1 * v1 + v2 * v2, red + 4);
    const float mu  = ts * (1.f / 768.f);
    const float var = ts2 * (1.f / 768.f) - mu * mu;
    const float rs  = rsqrtf(var + 1e-5f);
    float dot = 0.f;
    {
        float xv;
        xv = (v0 - mu) * rs * g[t]       + bt[t];       xn[(size_t)row * 768 + t]       = (bf16_t)xv; dot += xv * w_res[t];
        xv = (v1 - mu) * rs * g[t + 256] + bt[t + 256]; xn[(size_t)row * 768 + t + 256] = (bf16_t)xv; dot += xv * w_res[t + 256];
        xv = (v2 - mu) * rs * g[t + 512] + bt[t + 512]; xn[(size_t)row * 768 + t + 512] = (bf16_t)xv; dot += xv * w_res[t + 512];
    }
    const float td = block_sum256(dot, red + 8);
    if (t == 0) residue[row] = 1.f / (1.f + expf(-(td + b_res[0])));
}

// column mean accumulate: xmean[b,d] += sum over 128 tokens
__global__ void kcolmean(const bf16_t* __restrict__ xn, float* __restrict__ xmean)
{
    const int b = blockIdx.x, dc = blockIdx.y, nc = blockIdx.z;
    const int d = dc * 256 + threadIdx.x;
    const bf16_t* p = xn + (size_t)(b * 1024 + nc * 128) * 768 + d;
    float s = 0.f;
#pragma unroll 4
    for (int n = 0; n < 128; ++n) s += (float)p[(size_t)n * 768];
    atomicAdd(&xmean[b * 768 + d], s);
}

// read/write gates + wmean; one block of 64 threads (b,h)
__global__ void kgates(const float* __restrict__ xmean,
                       const float* __restrict__ w_rg, const float* __restrict__ b_rg,
                       const float* __restrict__ w_wg, const float* __restrict__ b_wg,
                       float* __restrict__ read_g, float* __restrict__ wmean)
{
    __shared__ float wg[64];
    const int t = threadIdx.x, b = t >> 3, h = t & 7;
    float dr = 0.f, dw = 0.f;
    for (int d = 0; d < 768; ++d) {
        const float xm = xmean[b * 768 + d] * (1.f / 1024.f);
        dr += xm * w_rg[d * 8 + h];
        dw += xm * w_wg[d * 8 + h];
    }
    read_g[t] = 1.f / (1.f + expf(-(dr + b_rg[h])));
    wg[t]     = 1.f / (1.f + expf(-(dw + b_wg[h])));
    __syncthreads();
    if (t < 8) {
        float s = 0.f;
#pragma unroll
        for (int b2 = 0; b2 < 8; ++b2) s += wg[b2 * 8 + t];
        wmean[t] = s * 0.125f;
    }
}

// qkv GEMM over a CHUNK of batches.
// A = xn_chunk [CHUNK*1024, 768]; BT = w_inT [9216, 768].
__global__ void __launch_bounds__(256) kgemm_qkv(
    const bf16_t* __restrict__ xnc, const bf16_t* __restrict__ w_inT,
    const float* __restrict__ b_in,
    bf16_t* __restrict__ qfc, bf16_t* __restrict__ kTc, bf16_t* __restrict__ vTc,
    float* __restrict__ ksum_c, int nrt /* CHUNK*8 row tiles */)
{
    __shared__ __align__(16) bf16_t As[4096], Bs[4096];
    int bx, by;
    band_map(blockIdx.y * 72 + blockIdx.x, nrt, bx, by);
    const int row0 = by * 128, col0 = bx * 128;
    f32x4 acc[4][4];
    gemm128_bt(xnc, 768, w_inT, 768, 768, row0, col0, As, Bs, acc);

    const int lane = threadIdx.x & 63, wid = threadIdx.x >> 6;
    const int wr = wid >> 1, wc = wid & 1;
    const int third = col0 / 3072;

    if (third == 0) {
        // q path: bias + phi, row-major store
#pragma unroll
        for (int m = 0; m < 4; ++m) {
#pragma unroll
            for (int n2 = 0; n2 < 4; ++n2) {
                const int col  = col0 + wc * 64 + n2 * 16 + (lane & 15);
                const float bias = b_in[col];
#pragma unroll
                for (int r = 0; r < 4; ++r) {
                    const int row = row0 + wr * 64 + m * 16 + (lane >> 4) * 4 + r;
                    const float v = acc[m][n2][r] + bias;
                    const float u = fmaxf(v, 0.f) + 1e-6f;
                    qfc[(size_t)row * 3072 + col] = (bf16_t)(u * sqrtf(u));
                }
            }
        }
    } else {
        // k/v path: bias (+phi for k), transposed store [bh][d][n], ksum atomics
        const int lb  = row0 >> 10;                 // local batch
        const int nb  = (row0 & 1023) + wr * 64 + (lane >> 4) * 4;
        const int sl0 = col0 - third * 3072;        // 0..3071
        const int h   = sl0 / 384;
        bf16_t* dstT = ((third == 1) ? kTc : vTc) + (size_t)(lb * 8 + h) * 384 * 1024;
        float* ksrow = ksum_c + (size_t)(lb * 8 + h) * 384;
#pragma unroll
        for (int n2 = 0; n2 < 4; ++n2) {
            const int d   = (sl0 % 384) + wc * 64 + n2 * 16 + (lane & 15);
            const int col = col0 + wc * 64 + n2 * 16 + (lane & 15);
            const float bias = b_in[col];
            float ksp = 0.f;
#pragma unroll
            for (int m = 0; m < 4; ++m) {
                bf16x4 pk;
#pragma unroll
                for (int r = 0; r < 4; ++r) {
                    float v = acc[m][n2][r] + bias;
                    if (third == 1) { const float u = fmaxf(v, 0.f) + 1e-6f; v = u * sqrtf(u); ksp += v; }
                    pk[r] = (bf16_t)v;
                }
                *(bf16x4*)&dstT[(size_t)d * 1024 + nb + m * 16] = pk;
            }
            if (third == 1) atomicAdd(&ksrow[d], ksp);
        }
    }
}

// state GEMM per local (b,h): C[d,e] = sum_n kT[d,n] vT[e,n];
// scale rows by 1/(ksum+eps), accumulate into ssum[h]
__global__ void __launch_bounds__(256) kgemm_state(
    const bf16_t* __restrict__ kTc, const bf16_t* __restrict__ vTc,
    const float* __restrict__ ksum_c, float* __restrict__ ssum)
{
    __shared__ __align__(16) bf16_t As[4096], Bs[4096];
    const int lbh = blockIdx.z, h = lbh & 7;
    const int row0 = blockIdx.y * 128, col0 = blockIdx.x * 128;
    const bf16_t* A  = kTc + (size_t)lbh * 393216;
    const bf16_t* BT = vTc + (size_t)lbh * 393216;
    f32x4 acc[4][4];
    gemm128_bt(A, 1024, BT, 1024, 1024, row0, col0, As, Bs, acc);

    const int lane = threadIdx.x & 63, wid = threadIdx.x >> 6;
    const int wr = wid >> 1, wc = wid & 1;
    float* ss = ssum + (size_t)h * 147456;
#pragma unroll
    for (int m = 0; m < 4; ++m) {
#pragma unroll
        for (int r = 0; r < 4; ++r) {
            const int d = row0 + wr * 64 + m * 16 + (lane >> 4) * 4 + r;
            const float sc = 1.f / (ksum_c[(size_t)lbh * 384 + d] + 1e-6f);
#pragma unroll
            for (int n = 0; n < 4; ++n) {
                const int e = col0 + wc * 64 + n * 16 + (lane & 15);
                atomicAdd(&ss[(size_t)d * 384 + e], acc[m][n][r] * sc);
            }
        }
    }
}

// mem_newT[h,e,d] = bf16(0.95*mem[h,d,e] + (0.05*wmean[h]/8)*ssum[h,d,e])
__global__ void kmemupd(const float* __restrict__ mem, const float* __restrict__ ssum,
                        const float* __restrict__ wmean, bf16_t* __restrict__ memT)
{
    __shared__ float tl[32][33];
    const int h = blockIdx.z;
    const int e0 = blockIdx.x * 32, d0 = blockIdx.y * 32;
    const int tx = threadIdx.x, ty = threadIdx.y;
    const size_t base = (size_t)h * 147456;
    const float wm = wmean[h] * (0.05f / 8.f);
#pragma unroll
    for (int i = ty; i < 32; i += 8) {
        const size_t idx = base + (size_t)(d0 + i) * 384 + e0 + tx;
        tl[i][tx] = 0.95f * mem[idx] + wm * ssum[idx];
    }
    __syncthreads();
#pragma unroll
    for (int i = ty; i < 32; i += 8)
        memT[base + (size_t)(e0 + i) * 384 + d0 + tx] = (bf16_t)tl[tx][i];
}

// y GEMM: per (b,h) C[n,e] = q[n,:] @ memT[e,:]; scale by read gate
__global__ void __launch_bounds__(256) kgemm_y(
    const bf16_t* __restrict__ qf, const bf16_t* __restrict__ memT,
    const float* __restrict__ read_g, bf16_t* __restrict__ yf)
{
    __shared__ __align__(16) bf16_t As[4096], Bs[4096];
    const int bh = blockIdx.z, b = bh >> 3, h = bh & 7;
    const int row0 = blockIdx.y * 128, col0 = blockIdx.x * 128;
    const bf16_t* A  = qf + (size_t)b * 1024 * 3072 + (size_t)h * 384;
    const bf16_t* BT = memT + (size_t)h * 147456;
    f32x4 acc[4][4];
    gemm128_bt(A, 3072, BT, 384, 384, row0, col0, As, Bs, acc);

    const float rg = read_g[bh];
    const int lane = threadIdx.x & 63, wid = threadIdx.x >> 6;
    const int wr = wid >> 1, wc = wid & 1;
#pragma unroll
    for (int m = 0; m < 4; ++m) {
#pragma unroll
        for (int n = 0; n < 4; ++n) {
            const int col = col0 + wc * 64 + n * 16 + (lane & 15);
#pragma unroll
            for (int r = 0; r < 4; ++r) {
                const int row = row0 + wr * 64 + m * 16 + (lane >> 4) * 4 + r;
                yf[(size_t)(b * 1024 + row) * 3072 + h * 384 + col] = (bf16_t)(acc[m][n][r] * rg);
            }
        }
    }
}

// out GEMM: C = yf @ w_out + b_out; out = residue*C + (1-residue)*x
__global__ void __launch_bounds__(256) kgemm_out(
    const bf16_t* __restrict__ yf, const bf16_t* __restrict__ w_outT,
    const float* __restrict__ b_out, const float* __restrict__ residue,
    const float* __restrict__ x, float* __restrict__ out)
{
    __shared__ __align__(16) bf16_t As[4096], Bs[4096];
    int bx, by;
    band_map(blockIdx.y * 6 + blockIdx.x, 64, bx, by);
    const int row0 = by * 128, col0 = bx * 128;
    f32x4 acc[4][4];
    gemm128_bt(yf, 3072, w_outT, 3072, 3072, row0, col0, As, Bs, acc);

    const int lane = threadIdx.x & 63, wid = threadIdx.x >> 6;
    const int wr = wid >> 1, wc = wid & 1;
#pragma unroll
    for (int m = 0; m < 4; ++m) {
#pragma unroll
        for (int n = 0; n < 4; ++n) {
            const int col = col0 + wc * 64 + n * 16 + (lane & 15);
            const float bias = b_out[col];
#pragma unroll
            for (int r = 0; r < 4; ++r) {
                const int row = row0 + wr * 64 + m * 16 + (lane >> 4) * 4 + r;
                const float v = acc[m][n][r] + bias;
                const float rr = residue[row];
                out[(size_t)row * 768 + col] = rr * v + (1.f - rr) * x[(size_t)row * 768 + col];
            }
        }
    }
}

// ---------------------------------------------------------------------------
extern "C" void kernel_launch(void* const* d_in, const int* in_sizes, int n_in,
                              void* d_out, int out_size, void* d_ws, size_t ws_size,
                              hipStream_t stream)
{
    (void)in_sizes; (void)n_in; (void)out_size;
    const float* x     = (const float*)d_in[0];
    const float* mem   = (const float*)d_in[1];
    const float* ln_g  = (const float*)d_in[2];
    const float* ln_b  = (const float*)d_in[3];
    const float* w_in  = (const float*)d_in[4];
    const float* b_in  = (const float*)d_in[5];
    const float* w_out = (const float*)d_in[6];
    const float* b_out = (const float*)d_in[7];
    const float* w_rg  = (const float*)d_in[8];
    const float* b_rg  = (const float*)d_in[9];
    const float* w_wg  = (const float*)d_in[10];
    const float* b_wg  = (const float*)d_in[11];
    const float* w_res = (const float*)d_in[12];
    const float* b_res = (const float*)d_in[13];
    float* out = (float*)d_out;

    // pick largest CHUNK (batches per qkv/state launch pair) that fits ws
    auto total_for = [&](int c) -> size_t {
        size_t o = 0;
        auto a = [&](size_t b) { o += (b + 255) & ~(size_t)255; };
        a(50331648);                       // qf
        a(14155776); a(12582912);          // w_inT, xn (overlay head)
        a((size_t)c * 6291456);            // kTc
        a((size_t)c * 6291456);            // vTc
        a(4718592); a(4718592); a(2359296);// w_outT, ssum, memT
        a(32768); a(24576); a(98304); a(256); a(256); // residue,xmean,ksum,read_g,wmean
        return o;
    };
    int CHUNK = 0;
    for (int c = 8; c >= 2; c >>= 1) if (total_for(c) <= ws_size) { CHUNK = c; break; }
    if (CHUNK == 0) return;                // fail soft

    char* ws = (char*)d_ws;
    size_t off = 0;
    auto alloc = [&](size_t bytes) -> char* {
        char* p = ws + off; off += (bytes + 255) & ~(size_t)255; return p;
    };
    bf16_t* qf     = (bf16_t*)alloc(50331648);
    bf16_t* yf     = (bf16_t*)(ws + off);   // overlay: w_inT..vTc (>= 48 MB for CHUNK>=2)
    bf16_t* w_inT  = (bf16_t*)alloc(14155776);
    bf16_t* xn     = (bf16_t*)alloc(12582912);
    bf16_t* kTc    = (bf16_t*)alloc((size_t)CHUNK * 6291456);
    bf16_t* vTc    = (bf16_t*)alloc((size_t)CHUNK * 6291456);
    bf16_t* w_outT = (bf16_t*)alloc(4718592);
    float*  ssum   = (float*) alloc(4718592);
    bf16_t* memT   = (bf16_t*)alloc(2359296);
    float*  residue= (float*) alloc(32768);
    float*  xmean  = (float*) alloc(24576);
    float*  ksum   = (float*) alloc(98304);          // [64][384] global bh
    float*  read_g = (float*) alloc(256);
    float*  wmean  = (float*) alloc(256);

    hipMemsetAsync(xmean, 0, 24576, stream);
    hipMemsetAsync(ksum,  0, 98304, stream);
    hipMemsetAsync(ssum,  0, 4718592, stream);

    ktrans_w<<<dim3(288, 24), dim3(32, 8), 0, stream>>>(w_in, w_inT, 768, 9216);
    ktrans_w<<<dim3(24, 96), dim3(32, 8), 0, stream>>>(w_out, w_outT, 3072, 768);
    kln<<<8192, 256, 0, stream>>>(x, ln_g, ln_b, w_res, b_res, xn, residue);
    kcolmean<<<dim3(8, 3, 8), 256, 0, stream>>>(xn, xmean);
    kgates<<<1, 64, 0, stream>>>(xmean, w_rg, b_rg, w_wg, b_wg, read_g, wmean);

    const int NC = 8 / CHUNK;
    for (int c = 0; c < NC; ++c) {
        const int b0 = c * CHUNK;
        kgemm_qkv<<<dim3(72, CHUNK * 8), 256, 0, stream>>>(
            xn + (size_t)b0 * 1024 * 768, w_inT, b_in,
            qf + (size_t)b0 * 1024 * 3072, kTc, vTc,
            ksum + (size_t)b0 * 8 * 384, CHUNK * 8);
        kgemm_state<<<dim3(3, 3, CHUNK * 8), 256, 0, stream>>>(
            kTc, vTc, ksum + (size_t)b0 * 8 * 384, ssum);
    }

    kmemupd<<<dim3(12, 12, 8), dim3(32, 8), 0, stream>>>(mem, ssum, wmean, memT);
    kgemm_y<<<dim3(3, 8, 64), 256, 0, stream>>>(qf, memT, read_g, yf);
    kgemm_out<<<dim3(6, 64), 256, 0, stream>>>(yf, w_outT, b_out, residue, x, out);
}

// Round 6
// 405.007 us; speedup vs baseline: 1.2824x; 1.1862x over previous
//
#include <hip/hip_runtime.h>
#include <hip/hip_bf16.h>
#include <cstdint>
#include <cstddef>

// ---------------------------------------------------------------------------
// BDH Linear Attention (B=8,N=1024,D=768,H=8,S=3072,HD=384) on gfx950
// Round 6: qkv GEMM -> 256x256 tile, BK=64, 8 waves (2Mx4N), LDS 128KB dbuf,
//          same proven 2-phase barrier structure (schedule change deferred).
//          kgates parallelized. Everything else = r5 (verified).
// ---------------------------------------------------------------------------

typedef __bf16 bf16_t;
typedef bf16_t bf16x4 __attribute__((ext_vector_type(4)));
typedef bf16_t bf16x8 __attribute__((ext_vector_type(8)));
typedef float f32x4 __attribute__((ext_vector_type(4)));

// ---------------- 128^2 GEMM mainloop (r3-proven, used by state/y/out) ------
__device__ __forceinline__ void gemm128_bt(
    const bf16_t* __restrict__ A, int lda,
    const bf16_t* __restrict__ BT, int ldb,
    int K, int row0, int col0,
    bf16_t* As, bf16_t* Bs, f32x4 acc[4][4])
{
    const int t    = threadIdx.x;
    const int lane = t & 63;
    const int wid  = t >> 6;
    const int wr   = wid >> 1, wc = wid & 1;
    const int fr   = lane & 15;
    const int fk   = (lane >> 4) * 8;

#pragma unroll
    for (int m = 0; m < 4; ++m)
#pragma unroll
        for (int n = 0; n < 4; ++n)
            acc[m][n] = (f32x4){0.f, 0.f, 0.f, 0.f};

    const int rr = lane >> 2;
    const int rc = (lane & 3) * 8;

    for (int k0 = 0; k0 < K; k0 += 32) {
#pragma unroll
        for (int c = 0; c < 2; ++c) {
            const int q = wid * 2 + c;
            __builtin_amdgcn_global_load_lds(
                (const __attribute__((address_space(1))) void*)(A + (size_t)(row0 + q * 16 + rr) * lda + (k0 + rc)),
                (__attribute__((address_space(3))) void*)(As + q * 512), 16, 0, 0);
            __builtin_amdgcn_global_load_lds(
                (const __attribute__((address_space(1))) void*)(BT + (size_t)(col0 + q * 16 + rr) * ldb + (k0 + rc)),
                (__attribute__((address_space(3))) void*)(Bs + q * 512), 16, 0, 0);
        }
        __syncthreads();

        bf16x8 av[4], bv[4];
#pragma unroll
        for (int m = 0; m < 4; ++m)
            av[m] = *(const bf16x8*)&As[(wr * 64 + m * 16 + fr) * 32 + fk];
#pragma unroll
        for (int n = 0; n < 4; ++n)
            bv[n] = *(const bf16x8*)&Bs[(wc * 64 + n * 16 + fr) * 32 + fk];
#pragma unroll
        for (int m = 0; m < 4; ++m)
#pragma unroll
            for (int n = 0; n < 4; ++n)
                acc[m][n] = __builtin_amdgcn_mfma_f32_16x16x32_bf16(av[m], bv[n], acc[m][n], 0, 0, 0);
        __syncthreads();
    }
}

// XCD band remap (r5-proven: FETCH 456->100MB on qkv)
__device__ __forceinline__ void band_map(int flat, int nby, int& bx, int& by)
{
    const int xcd = flat & 7;
    const int seq = flat >> 3;
    const int bandsz = nby >> 3;
    by = xcd * bandsz + (seq % bandsz);
    bx = seq / bandsz;
}

// ---------------- small kernels --------------------------------------------

__global__ void ktrans_w(const float* __restrict__ in, bf16_t* __restrict__ out, int R, int C)
{
    __shared__ float tl[32][33];
    const int c0 = blockIdx.x * 32, r0 = blockIdx.y * 32;
    const int tx = threadIdx.x, ty = threadIdx.y;
#pragma unroll
    for (int i = ty; i < 32; i += 8) tl[i][tx] = in[(size_t)(r0 + i) * C + c0 + tx];
    __syncthreads();
#pragma unroll
    for (int i = ty; i < 32; i += 8) out[(size_t)(c0 + i) * R + r0 + tx] = (bf16_t)tl[tx][i];
}

__device__ __forceinline__ float block_sum256(float v, float* s4)
{
#pragma unroll
    for (int off = 32; off > 0; off >>= 1) v += __shfl_down(v, off);
    const int lane = threadIdx.x & 63, w = threadIdx.x >> 6;
    if (lane == 0) s4[w] = v;
    __syncthreads();
    return s4[0] + s4[1] + s4[2] + s4[3];
}

__global__ void __launch_bounds__(256) kln(
    const float* __restrict__ x, const float* __restrict__ g, const float* __restrict__ bt,
    const float* __restrict__ w_res, const float* __restrict__ b_res,
    bf16_t* __restrict__ xn, float* __restrict__ residue)
{
    __shared__ float red[12];
    const int row = blockIdx.x;
    const float* xr = x + (size_t)row * 768;
    const int t = threadIdx.x;
    const float v0 = xr[t], v1 = xr[t + 256], v2 = xr[t + 512];
    const float ts  = block_sum256(v0 + v1 + v2, red);
    const float ts2 = block_sum256(v0 * v0 + v1 * v1 + v2 * v2, red + 4);
    const float mu  = ts * (1.f / 768.f);
    const float var = ts2 * (1.f / 768.f) - mu * mu;
    const float rs  = rsqrtf(var + 1e-5f);
    float dot = 0.f;
    {
        float xv;
        xv = (v0 - mu) * rs * g[t]       + bt[t];       xn[(size_t)row * 768 + t]       = (bf16_t)xv; dot += xv * w_res[t];
        xv = (v1 - mu) * rs * g[t + 256] + bt[t + 256]; xn[(size_t)row * 768 + t + 256] = (bf16_t)xv; dot += xv * w_res[t + 256];
        xv = (v2 - mu) * rs * g[t + 512] + bt[t + 512]; xn[(size_t)row * 768 + t + 512] = (bf16_t)xv; dot += xv * w_res[t + 512];
    }
    const float td = block_sum256(dot, red + 8);
    if (t == 0) residue[row] = 1.f / (1.f + expf(-(td + b_res[0])));
}

__global__ void kcolmean(const bf16_t* __restrict__ xn, float* __restrict__ xmean)
{
    const int b = blockIdx.x, dc = blockIdx.y, nc = blockIdx.z;
    const int d = dc * 256 + threadIdx.x;
    const bf16_t* p = xn + (size_t)(b * 1024 + nc * 128) * 768 + d;
    float s = 0.f;
#pragma unroll 4
    for (int n = 0; n < 128; ++n) s += (float)p[(size_t)n * 768];
    atomicAdd(&xmean[b * 768 + d], s);
}

// read/write gates + wmean; 256 threads: 64 (b,h) groups x 4 partials
__global__ void __launch_bounds__(256) kgates(
    const float* __restrict__ xmean,
    const float* __restrict__ w_rg, const float* __restrict__ b_rg,
    const float* __restrict__ w_wg, const float* __restrict__ b_wg,
    float* __restrict__ read_g, float* __restrict__ wmean)
{
    __shared__ float pr[64][4], pw[64][4], wg[64];
    const int t = threadIdx.x, grp = t >> 2, qtr = t & 3;
    const int b = grp >> 3, h = grp & 7;
    float dr = 0.f, dw = 0.f;
    for (int d = qtr * 192; d < qtr * 192 + 192; ++d) {
        const float xm = xmean[b * 768 + d] * (1.f / 1024.f);
        dr += xm * w_rg[d * 8 + h];
        dw += xm * w_wg[d * 8 + h];
    }
    pr[grp][qtr] = dr; pw[grp][qtr] = dw;
    __syncthreads();
    if (qtr == 0) {
        const float sr = pr[grp][0] + pr[grp][1] + pr[grp][2] + pr[grp][3];
        const float sw = pw[grp][0] + pw[grp][1] + pw[grp][2] + pw[grp][3];
        read_g[grp] = 1.f / (1.f + expf(-(sr + b_rg[h])));
        wg[grp]     = 1.f / (1.f + expf(-(sw + b_wg[h])));
    }
    __syncthreads();
    if (t < 8) {
        float s = 0.f;
#pragma unroll
        for (int b2 = 0; b2 < 8; ++b2) s += wg[b2 * 8 + t];
        wmean[t] = s * 0.125f;
    }
}

// ---------------- qkv GEMM: 256x256 tile, BK=64, 8 waves, 2-phase dbuf ------
// LDS buf (64KB): A at [0,16384), B at [16384,32768) elems; each op laid out
// [s][256][32] (s = K-half), rows 64B. Staged linearly (gload_lds), frag reads
// at row-stride 64B -> 8-way bank alias (r3-proven hidden at 2-phase).
__global__ void __launch_bounds__(512, 2) kgemm_qkv256(
    const bf16_t* __restrict__ xnc, const bf16_t* __restrict__ w_inT,
    const float* __restrict__ b_in,
    bf16_t* __restrict__ qfc, bf16_t* __restrict__ kTc, bf16_t* __restrict__ vTc,
    float* __restrict__ ksum_c, int nrt /* CHUNK*4 row tiles */)
{
    __shared__ __align__(16) bf16_t L[65536];          // 128 KB, 2 bufs
    const int t = threadIdx.x, lane = t & 63, wid = t >> 6;
    const int wr = wid >> 2, wc = wid & 3;             // 2M x 4N waves
    int bx, by;
    band_map(blockIdx.y * 36 + blockIdx.x, nrt, bx, by);
    const int row0 = by * 256, col0 = bx * 256;

    f32x4 acc[8][4];
#pragma unroll
    for (int m = 0; m < 8; ++m)
#pragma unroll
        for (int n = 0; n < 4; ++n)
            acc[m][n] = (f32x4){0.f, 0.f, 0.f, 0.f};

    // staging lane constants
    const int grow = 16 * wid + (lane >> 2);           // + 128*j
    const int gcol = (lane & 3) * 8;                   // + 32*s
    const int ldst = 512 * wid + 8 * lane;             // + 4096*j + 8192*s

    auto stage = [&](int buf, int k0) {
        bf16_t* base = &L[buf * 32768];
#pragma unroll
        for (int op = 0; op < 2; ++op) {
            const bf16_t* src = op ? w_inT : xnc;
            const int r0 = op ? col0 : row0;
#pragma unroll
            for (int s = 0; s < 2; ++s)
#pragma unroll
                for (int j = 0; j < 2; ++j)
                    __builtin_amdgcn_global_load_lds(
                        (const __attribute__((address_space(1))) void*)(src + (size_t)(r0 + 128 * j + grow) * 768 + (k0 + 32 * s + gcol)),
                        (__attribute__((address_space(3))) void*)(base + op * 16384 + s * 8192 + j * 4096 + ldst),
                        16, 0, 0);
        }
    };

    const int fr = lane & 15, fo = (lane >> 4) * 8;

    stage(0, 0);
    __syncthreads();
    int cur = 0;
    for (int k0 = 0; k0 < 768; k0 += 64) {
        if (k0 + 64 < 768) stage(cur ^ 1, k0 + 64);
        const bf16_t* base = &L[cur * 32768];
#pragma unroll
        for (int s = 0; s < 2; ++s) {
            bf16x8 bv[4];
#pragma unroll
            for (int n = 0; n < 4; ++n)
                bv[n] = *(const bf16x8*)&base[16384 + s * 8192 + (wc * 64 + n * 16 + fr) * 32 + fo];
#pragma unroll
            for (int m = 0; m < 8; ++m) {
                const bf16x8 av = *(const bf16x8*)&base[s * 8192 + (wr * 128 + m * 16 + fr) * 32 + fo];
#pragma unroll
                for (int n = 0; n < 4; ++n)
                    acc[m][n] = __builtin_amdgcn_mfma_f32_16x16x32_bf16(av, bv[n], acc[m][n], 0, 0, 0);
            }
        }
        __syncthreads();
        cur ^= 1;
    }

    const int third = col0 / 3072;
    if (third == 0) {
        // q path: bias + phi, row-major store
#pragma unroll
        for (int m = 0; m < 8; ++m) {
#pragma unroll
            for (int n2 = 0; n2 < 4; ++n2) {
                const int col  = col0 + wc * 64 + n2 * 16 + fr;
                const float bias = b_in[col];
#pragma unroll
                for (int r = 0; r < 4; ++r) {
                    const int row = row0 + wr * 128 + m * 16 + (lane >> 4) * 4 + r;
                    const float v = acc[m][n2][r] + bias;
                    const float u = fmaxf(v, 0.f) + 1e-6f;
                    qfc[(size_t)row * 3072 + col] = (bf16_t)(u * sqrtf(u));
                }
            }
        }
    } else {
        // k/v path: bias (+phi for k), transposed store [bh][d][n], ksum atomics
        const int lb  = row0 >> 10;
        const int nbb = (row0 & 1023) + wr * 128 + (lane >> 4) * 4;
#pragma unroll
        for (int n2 = 0; n2 < 4; ++n2) {
            const int colg = col0 + wc * 64 + n2 * 16 + fr;
            const int coll = colg - third * 3072;
            const int h = coll / 384, d = coll % 384;
            bf16_t* dstT = ((third == 1) ? kTc : vTc) + (size_t)(lb * 8 + h) * 393216;
            const float bias = b_in[colg];
            float ksp = 0.f;
#pragma unroll
            for (int m = 0; m < 8; ++m) {
                bf16x4 pk;
#pragma unroll
                for (int r = 0; r < 4; ++r) {
                    float v = acc[m][n2][r] + bias;
                    if (third == 1) { const float u = fmaxf(v, 0.f) + 1e-6f; v = u * sqrtf(u); ksp += v; }
                    pk[r] = (bf16_t)v;
                }
                *(bf16x4*)&dstT[(size_t)d * 1024 + nbb + m * 16] = pk;
            }
            if (third == 1) atomicAdd(&ksum_c[(size_t)(lb * 8 + h) * 384 + d], ksp);
        }
    }
}

// state GEMM per local (b,h)
__global__ void __launch_bounds__(256) kgemm_state(
    const bf16_t* __restrict__ kTc, const bf16_t* __restrict__ vTc,
    const float* __restrict__ ksum_c, float* __restrict__ ssum)
{
    __shared__ __align__(16) bf16_t As[4096], Bs[4096];
    const int lbh = blockIdx.z, h = lbh & 7;
    const int row0 = blockIdx.y * 128, col0 = blockIdx.x * 128;
    const bf16_t* A  = kTc + (size_t)lbh * 393216;
    const bf16_t* BT = vTc + (size_t)lbh * 393216;
    f32x4 acc[4][4];
    gemm128_bt(A, 1024, BT, 1024, 1024, row0, col0, As, Bs, acc);

    const int lane = threadIdx.x & 63, wid = threadIdx.x >> 6;
    const int wr = wid >> 1, wc = wid & 1;
    float* ss = ssum + (size_t)h * 147456;
#pragma unroll
    for (int m = 0; m < 4; ++m) {
#pragma unroll
        for (int r = 0; r < 4; ++r) {
            const int d = row0 + wr * 64 + m * 16 + (lane >> 4) * 4 + r;
            const float sc = 1.f / (ksum_c[(size_t)lbh * 384 + d] + 1e-6f);
#pragma unroll
            for (int n = 0; n < 4; ++n) {
                const int e = col0 + wc * 64 + n * 16 + (lane & 15);
                atomicAdd(&ss[(size_t)d * 384 + e], acc[m][n][r] * sc);
            }
        }
    }
}

__global__ void kmemupd(const float* __restrict__ mem, const float* __restrict__ ssum,
                        const float* __restrict__ wmean, bf16_t* __restrict__ memT)
{
    __shared__ float tl[32][33];
    const int h = blockIdx.z;
    const int e0 = blockIdx.x * 32, d0 = blockIdx.y * 32;
    const int tx = threadIdx.x, ty = threadIdx.y;
    const size_t base = (size_t)h * 147456;
    const float wm = wmean[h] * (0.05f / 8.f);
#pragma unroll
    for (int i = ty; i < 32; i += 8) {
        const size_t idx = base + (size_t)(d0 + i) * 384 + e0 + tx;
        tl[i][tx] = 0.95f * mem[idx] + wm * ssum[idx];
    }
    __syncthreads();
#pragma unroll
    for (int i = ty; i < 32; i += 8)
        memT[base + (size_t)(e0 + i) * 384 + d0 + tx] = (bf16_t)tl[tx][i];
}

__global__ void __launch_bounds__(256) kgemm_y(
    const bf16_t* __restrict__ qf, const bf16_t* __restrict__ memT,
    const float* __restrict__ read_g, bf16_t* __restrict__ yf)
{
    __shared__ __align__(16) bf16_t As[4096], Bs[4096];
    const int bh = blockIdx.z, b = bh >> 3, h = bh & 7;
    const int row0 = blockIdx.y * 128, col0 = blockIdx.x * 128;
    const bf16_t* A  = qf + (size_t)b * 1024 * 3072 + (size_t)h * 384;
    const bf16_t* BT = memT + (size_t)h * 147456;
    f32x4 acc[4][4];
    gemm128_bt(A, 3072, BT, 384, 384, row0, col0, As, Bs, acc);

    const float rg = read_g[bh];
    const int lane = threadIdx.x & 63, wid = threadIdx.x >> 6;
    const int wr = wid >> 1, wc = wid & 1;
#pragma unroll
    for (int m = 0; m < 4; ++m) {
#pragma unroll
        for (int n = 0; n < 4; ++n) {
            const int col = col0 + wc * 64 + n * 16 + (lane & 15);
#pragma unroll
            for (int r = 0; r < 4; ++r) {
                const int row = row0 + wr * 64 + m * 16 + (lane >> 4) * 4 + r;
                yf[(size_t)(b * 1024 + row) * 3072 + h * 384 + col] = (bf16_t)(acc[m][n][r] * rg);
            }
        }
    }
}

__global__ void __launch_bounds__(256) kgemm_out(
    const bf16_t* __restrict__ yf, const bf16_t* __restrict__ w_outT,
    const float* __restrict__ b_out, const float* __restrict__ residue,
    const float* __restrict__ x, float* __restrict__ out)
{
    __shared__ __align__(16) bf16_t As[4096], Bs[4096];
    int bx, by;
    band_map(blockIdx.y * 6 + blockIdx.x, 64, bx, by);
    const int row0 = by * 128, col0 = bx * 128;
    f32x4 acc[4][4];
    gemm128_bt(yf, 3072, w_outT, 3072, 3072, row0, col0, As, Bs, acc);

    const int lane = threadIdx.x & 63, wid = threadIdx.x >> 6;
    const int wr = wid >> 1, wc = wid & 1;
#pragma unroll
    for (int m = 0; m < 4; ++m) {
#pragma unroll
        for (int n = 0; n < 4; ++n) {
            const int col = col0 + wc * 64 + n * 16 + (lane & 15);
            const float bias = b_out[col];
#pragma unroll
            for (int r = 0; r < 4; ++r) {
                const int row = row0 + wr * 64 + m * 16 + (lane >> 4) * 4 + r;
                const float v = acc[m][n][r] + bias;
                const float rr = residue[row];
                out[(size_t)row * 768 + col] = rr * v + (1.f - rr) * x[(size_t)row * 768 + col];
            }
        }
    }
}

// ---------------------------------------------------------------------------
extern "C" void kernel_launch(void* const* d_in, const int* in_sizes, int n_in,
                              void* d_out, int out_size, void* d_ws, size_t ws_size,
                              hipStream_t stream)
{
    (void)in_sizes; (void)n_in; (void)out_size;
    const float* x     = (const float*)d_in[0];
    const float* mem   = (const float*)d_in[1];
    const float* ln_g  = (const float*)d_in[2];
    const float* ln_b  = (const float*)d_in[3];
    const float* w_in  = (const float*)d_in[4];
    const float* b_in  = (const float*)d_in[5];
    const float* w_out = (const float*)d_in[6];
    const float* b_out = (const float*)d_in[7];
    const float* w_rg  = (const float*)d_in[8];
    const float* b_rg  = (const float*)d_in[9];
    const float* w_wg  = (const float*)d_in[10];
    const float* b_wg  = (const float*)d_in[11];
    const float* w_res = (const float*)d_in[12];
    const float* b_res = (const float*)d_in[13];
    float* out = (float*)d_out;

    auto total_for = [&](int c) -> size_t {
        size_t o = 0;
        auto a = [&](size_t b) { o += (b + 255) & ~(size_t)255; };
        a(50331648);                       // qf
        a(14155776); a(12582912);          // w_inT, xn (overlay head)
        a((size_t)c * 6291456);            // kTc
        a((size_t)c * 6291456);            // vTc
        a(4718592); a(4718592); a(2359296);// w_outT, ssum, memT
        a(32768); a(24576); a(98304); a(256); a(256);
        return o;
    };
    int CHUNK = 0;
    for (int c = 8; c >= 2; c >>= 1) if (total_for(c) <= ws_size) { CHUNK = c; break; }
    if (CHUNK == 0) return;                // fail soft

    char* ws = (char*)d_ws;
    size_t off = 0;
    auto alloc = [&](size_t bytes) -> char* {
        char* p = ws + off; off += (bytes + 255) & ~(size_t)255; return p;
    };
    bf16_t* qf     = (bf16_t*)alloc(50331648);
    bf16_t* yf     = (bf16_t*)(ws + off);   // overlay over w_inT..vTc
    bf16_t* w_inT  = (bf16_t*)alloc(14155776);
    bf16_t* xn     = (bf16_t*)alloc(12582912);
    bf16_t* kTc    = (bf16_t*)alloc((size_t)CHUNK * 6291456);
    bf16_t* vTc    = (bf16_t*)alloc((size_t)CHUNK * 6291456);
    bf16_t* w_outT = (bf16_t*)alloc(4718592);
    float*  ssum   = (float*) alloc(4718592);
    bf16_t* memT   = (bf16_t*)alloc(2359296);
    float*  residue= (float*) alloc(32768);
    float*  xmean  = (float*) alloc(24576);
    float*  ksum   = (float*) alloc(98304);
    float*  read_g = (float*) alloc(256);
    float*  wmean  = (float*) alloc(256);

    hipMemsetAsync(xmean, 0, 24576, stream);
    hipMemsetAsync(ksum,  0, 98304, stream);
    hipMemsetAsync(ssum,  0, 4718592, stream);

    ktrans_w<<<dim3(288, 24), dim3(32, 8), 0, stream>>>(w_in, w_inT, 768, 9216);
    ktrans_w<<<dim3(24, 96), dim3(32, 8), 0, stream>>>(w_out, w_outT, 3072, 768);
    kln<<<8192, 256, 0, stream>>>(x, ln_g, ln_b, w_res, b_res, xn, residue);
    kcolmean<<<dim3(8, 3, 8), 256, 0, stream>>>(xn, xmean);
    kgates<<<1, 256, 0, stream>>>(xmean, w_rg, b_rg, w_wg, b_wg, read_g, wmean);

    const int NC = 8 / CHUNK;
    for (int c = 0; c < NC; ++c) {
        const int b0 = c * CHUNK;
        kgemm_qkv256<<<dim3(36, CHUNK * 4), 512, 0, stream>>>(
            xn + (size_t)b0 * 1024 * 768, w_inT, b_in,
            qf + (size_t)b0 * 1024 * 3072, kTc, vTc,
            ksum + (size_t)b0 * 8 * 384, CHUNK * 4);
        kgemm_state<<<dim3(3, 3, CHUNK * 8), 256, 0, stream>>>(
            kTc, vTc, ksum + (size_t)b0 * 8 * 384, ssum);
    }

    kmemupd<<<dim3(12, 12, 8), dim3(32, 8), 0, stream>>>(mem, ssum, wmean, memT);
    kgemm_y<<<dim3(3, 8, 64), 256, 0, stream>>>(qf, memT, read_g, yf);
    kgemm_out<<<dim3(6, 64), 256, 0, stream>>>(yf, w_outT, b_out, residue, x, out);
}